// Round 4
// baseline (171.096 us; speedup 1.0000x reference)
//
#include <hip/hip_runtime.h>
#include <math.h>

#define NP   128
#define DIM  2048
#define NBLK 128
#define NTHR 256
#define MAGIC 0x5EED1234u

// Dynamic LDS layout (float offsets). 145,920 B total (<160 KiB/CU, 1 blk/CU).
#define OFF_PJ   0          // Pj[j][i]  128x132  (column/j-major P; Gram reads)
#define OFF_PR   16896      // Pr[i][j]  128x132  (row-major P; A-phase reads)
#define OFF_KERN 33792      // kern[16][132]      (this block's A-strip rows)
#define OFF_D    35904      // D[128]             (diag of Gram = |P_i|^2)
#define OFF_BINS 36032      // bins[256] (uint)   (radix-select histogram)
#define OFF_MISC 36288      // [0]=sel byte [1]=want | +4: rs_part[8][16] | +132: rowsum[16]
#define LDS_FLOATS 36480

extern __shared__ float smem[];

__device__ inline void diag_decode(int q, int& a, int& b) {
    // q in [0,448): strict-upper pair within an 8-aligned diagonal tile
    const int T = q / 28;
    int u = q - 28 * T, r = 0;
    while (u >= 7 - r) { u -= 7 - r; ++r; }
    a = 8 * T + r;
    b = 8 * T + r + 1 + u;
}

__global__ __launch_bounds__(NTHR, 1) void stein_fused(
    const float* __restrict__ var, const float* __restrict__ grad,
    float* __restrict__ out, float* __restrict__ Ppart,
    unsigned* __restrict__ slots)
{
    const int tid = threadIdx.x;
    const int b   = blockIdx.x;

    //===== S1: P partials. 16 output tiles (32x32) x 8 K-chunks (256) =========
    {
        const int t  = b & 15;
        const int ck = b >> 4;
        const int i0 = (t >> 2) * 32;
        const int j0 = (t & 3) * 32;
        const int tx = tid & 15, ty = tid >> 4;
        float* At = smem;          // [64][36] k-major var rows
        float* Bt = smem + 2304;   // [64][36] k-major grad rows
        const int lrow = 2 * ty + (tx >> 3);   // 0..31
        const int lcol = 4 * (tx & 7);         // 0,4,..,28
        float4 acc = {0.f, 0.f, 0.f, 0.f};
        for (int s = 0; s < 4; ++s) {
            const int kb = ck * 256 + s * 64;
            __syncthreads();
            #pragma unroll
            for (int p = 0; p < 2; ++p) {
                const int f  = tid + p * 256;
                const int r  = f >> 4;
                const int kq = (f & 15) * 4;
                const float4 a4 = *(const float4*)(var  + (i0 + r) * DIM + kb + kq);
                const float4 g4 = *(const float4*)(grad + (j0 + r) * DIM + kb + kq);
                At[(kq+0)*36 + r] = a4.x; At[(kq+1)*36 + r] = a4.y;
                At[(kq+2)*36 + r] = a4.z; At[(kq+3)*36 + r] = a4.w;
                Bt[(kq+0)*36 + r] = g4.x; Bt[(kq+1)*36 + r] = g4.y;
                Bt[(kq+2)*36 + r] = g4.z; Bt[(kq+3)*36 + r] = g4.w;
            }
            __syncthreads();
            #pragma unroll 8
            for (int k = 0; k < 64; ++k) {
                const float  a  = At[k*36 + lrow];
                const float4 b4 = *(const float4*)&Bt[k*36 + lcol];
                acc.x = fmaf(a, b4.x, acc.x);
                acc.y = fmaf(a, b4.y, acc.y);
                acc.z = fmaf(a, b4.z, acc.z);
                acc.w = fmaf(a, b4.w, acc.w);
            }
        }
        // device-scope stores -> coherence point (cross-XCD visible, no L2 flush)
        float* dst = Ppart + ck * (NP*NP) + (i0 + lrow) * NP + j0 + lcol;
        __hip_atomic_store(&dst[0], acc.x, __ATOMIC_RELAXED, __HIP_MEMORY_SCOPE_AGENT);
        __hip_atomic_store(&dst[1], acc.y, __ATOMIC_RELAXED, __HIP_MEMORY_SCOPE_AGENT);
        __hip_atomic_store(&dst[2], acc.z, __ATOMIC_RELAXED, __HIP_MEMORY_SCOPE_AGENT);
        __hip_atomic_store(&dst[3], acc.w, __ATOMIC_RELAXED, __HIP_MEMORY_SCOPE_AGENT);
    }

    //===== Custom grid barrier (slots poisoned 0xAA by harness each launch) ===
    __syncthreads();   // all waves drain vmem before the release store
    if (tid == 0)
        __hip_atomic_store(&slots[b], MAGIC, __ATOMIC_RELEASE, __HIP_MEMORY_SCOPE_AGENT);
    if (tid < 64) {
        unsigned spins = 0;
        bool ok = false;
        while (!ok && spins < 2000000u) {
            const unsigned s0 = __hip_atomic_load(&slots[tid],      __ATOMIC_RELAXED, __HIP_MEMORY_SCOPE_AGENT);
            const unsigned s1 = __hip_atomic_load(&slots[tid + 64], __ATOMIC_RELAXED, __HIP_MEMORY_SCOPE_AGENT);
            ok = (bool)__all((s0 == MAGIC) && (s1 == MAGIC));
            ++spins;
        }
    }
    __threadfence();
    __syncthreads();

    //===== Assembly: P = sum of 8 partials -> LDS in both layouts =============
    {
        const int i  = tid >> 1;
        const int jh = (tid & 1) * 64;
        float4 s[16];
        #pragma unroll
        for (int q = 0; q < 16; ++q) s[q] = {0.f, 0.f, 0.f, 0.f};
        for (int c = 0; c < 8; ++c) {
            const float* src = Ppart + c * (NP*NP) + i * NP + jh;
            #pragma unroll
            for (int q = 0; q < 16; ++q) {
                const float4 v = *(const float4*)(src + 4*q);
                s[q].x += v.x; s[q].y += v.y; s[q].z += v.z; s[q].w += v.w;
            }
        }
        #pragma unroll
        for (int q = 0; q < 16; ++q) {
            *(float4*)&smem[OFF_PR + i*132 + jh + 4*q] = s[q];
            const int j = jh + 4*q;
            smem[OFF_PJ + (j+0)*132 + i] = s[q].x;
            smem[OFF_PJ + (j+1)*132 + i] = s[q].y;
            smem[OFF_PJ + (j+2)*132 + i] = s[q].z;
            smem[OFF_PJ + (j+3)*132 + i] = s[q].w;
        }
    }
    __syncthreads();

    //===== Diag-tile pairs (448 same-8-group dots) + row norms D ==============
    float dv1 = 0.f, dv2 = 0.f, dnorm = 0.f;
    int a1, b1, a2 = 0, b2 = 0;
    const bool has2 = (tid < 192);
    diag_decode(tid, a1, b1);
    if (has2) diag_decode(256 + tid, a2, b2);
    const bool hasNorm = (tid < NP);
    for (int j = 0; j < NP; ++j) {
        const float* pj = &smem[OFF_PJ + j*132];
        dv1 = fmaf(pj[a1], pj[b1], dv1);
        dv2 = fmaf(pj[a2], pj[b2], dv2);
        if (hasNorm) dnorm = fmaf(pj[tid], pj[tid], dnorm);
    }
    if (hasNorm) smem[OFF_D + tid] = dnorm;

    //===== Strict-upper Gram: 120 tiles (8x8), 2 threads/tile (k-halves) ======
    float gacc[64];
    #pragma unroll
    for (int u = 0; u < 64; ++u) gacc[u] = 0.f;
    int sty = 0, stx = 1;
    const int shalf = tid & 1;
    if (tid < 240) {
        const int sq = tid >> 1;
        int y = 0, base = 0;
        while (base + (15 - y) <= sq) { base += 15 - y; ++y; }
        sty = y; stx = y + 1 + (sq - base);
        const int j0s = shalf * 64;
        for (int j = j0s; j < j0s + 64; ++j) {
            const float* pj = &smem[OFF_PJ + j*132];
            float av[8], bv[8];
            { const float4 q0 = *(const float4*)&pj[8*sty];
              const float4 q1 = *(const float4*)&pj[8*sty + 4];
              av[0]=q0.x; av[1]=q0.y; av[2]=q0.z; av[3]=q0.w;
              av[4]=q1.x; av[5]=q1.y; av[6]=q1.z; av[7]=q1.w; }
            { const float4 q0 = *(const float4*)&pj[8*stx];
              const float4 q1 = *(const float4*)&pj[8*stx + 4];
              bv[0]=q0.x; bv[1]=q0.y; bv[2]=q0.z; bv[3]=q0.w;
              bv[4]=q1.x; bv[5]=q1.y; bv[6]=q1.z; bv[7]=q1.w; }
            #pragma unroll
            for (int r = 0; r < 8; ++r)
                #pragma unroll
                for (int c = 0; c < 8; ++c)
                    gacc[r*8+c] = fmaf(av[r], bv[c], gacc[r*8+c]);
        }
    }
    // combine k-halves (pair = adjacent lanes)
    #pragma unroll
    for (int u = 0; u < 64; ++u)
        gacc[u] += __shfl_xor(gacc[u], 1);

    __syncthreads();   // D visible

    //===== Convert Gram -> dMsd values (in registers) =========================
    if (tid < 240) {
        float Da[8], Db[8];
        #pragma unroll
        for (int e = 0; e < 8; ++e) {
            Da[e] = smem[OFF_D + 8*sty + e];
            Db[e] = smem[OFF_D + 8*stx + e];
        }
        #pragma unroll
        for (int u = 0; u < 64; ++u)
            gacc[u] = (Da[u>>3] + Db[u&7] - 2.0f*gacc[u]) * (1.0f/128.0f);
    }
    dv1 = (smem[OFF_D + a1] + smem[OFF_D + b1] - 2.0f*dv1) * (1.0f/128.0f);
    if (has2)
        dv2 = (smem[OFF_D + a2] + smem[OFF_D + b2] - 2.0f*dv2) * (1.0f/128.0f);

    //===== Exact median: 4-pass weighted radix-select (rank 8192) =============
    // weights: each strict-upper value x2, plus 128 virtual zeros (true diag).
    unsigned* bins = (unsigned*)&smem[OFF_BINS];
    unsigned* sel  = (unsigned*)&smem[OFF_MISC];
    unsigned prefix = 0, want = 8192;
    for (int pass = 0; pass < 4; ++pass) {
        const int sh = 24 - 8*pass;
        bins[tid] = 0u;
        __syncthreads();
        if (tid < 240 && shalf == 0) {
            #pragma unroll
            for (int u = 0; u < 64; ++u) {
                const unsigned v = __float_as_uint(gacc[u]);
                if (pass == 0 || (v >> (sh + 8)) == prefix)
                    atomicAdd(&bins[(v >> sh) & 255u], 2u);
            }
        }
        { const unsigned v = __float_as_uint(dv1);
          if (pass == 0 || (v >> (sh + 8)) == prefix)
              atomicAdd(&bins[(v >> sh) & 255u], 2u); }
        if (has2) {
            const unsigned v = __float_as_uint(dv2);
            if (pass == 0 || (v >> (sh + 8)) == prefix)
                atomicAdd(&bins[(v >> sh) & 255u], 2u);
        }
        if (tid == 0 && prefix == 0) atomicAdd(&bins[0], 128u);  // true-diag zeros
        __syncthreads();
        if (tid < 64) {
            unsigned c0 = bins[4*tid], c1 = bins[4*tid+1], c2 = bins[4*tid+2], c3 = bins[4*tid+3];
            const unsigned tot = c0 + c1 + c2 + c3;
            unsigned incl = tot;
            #pragma unroll
            for (int o = 1; o < 64; o <<= 1) {
                const unsigned n = __shfl_up(incl, o);
                if (tid >= o) incl += n;
            }
            unsigned cum = incl - tot;
            unsigned cc[4] = {c0, c1, c2, c3};
            #pragma unroll
            for (int e = 0; e < 4; ++e) {
                if (cum <= want && want < cum + cc[e]) {
                    sel[0] = (unsigned)(4*tid + e);
                    sel[1] = want - cum;
                }
                cum += cc[e];
            }
        }
        __syncthreads();
        prefix = (prefix << 8) | sel[0];
        want = sel[1];
        __syncthreads();
    }
    const float med   = __uint_as_float(prefix);
    const float h     = med * med * (1.0f / 4.852030263919617f);  // /ln(128)
    const float inv2h = 0.5f / h;
    const float invh  = 1.0f / h;

    //===== kern strip (rows R16..R16+15) for this block's out tile ============
    const int rg  = b >> 4;          // 0..7 row-group
    const int R16 = rg * 16;
    float* kern = &smem[OFF_KERN];   // [16][132]
    {
        const int tp0 = 2*rg, tp1 = 2*rg + 1;
        if (tid < 240 && shalf == 0) {
            const bool rmatch = (sty == tp0) | (sty == tp1);
            const bool cmatch = (stx == tp0) | (stx == tp1);
            if (rmatch | cmatch) {
                #pragma unroll
                for (int u = 0; u < 64; ++u) {
                    const float e = __expf(-gacc[u] * inv2h);
                    const int aa = 8*sty + (u >> 3), bb = 8*stx + (u & 7);
                    if (rmatch) kern[(aa - R16)*132 + bb] = e;
                    if (cmatch) kern[(bb - R16)*132 + aa] = e;
                }
            }
        }
        { const float e1 = __expf(-dv1 * inv2h);
          if (a1 >= R16 && a1 < R16 + 16) kern[(a1 - R16)*132 + b1] = e1;
          if (b1 >= R16 && b1 < R16 + 16) kern[(b1 - R16)*132 + a1] = e1; }
        if (has2) {
            const float e2 = __expf(-dv2 * inv2h);
            if (a2 >= R16 && a2 < R16 + 16) kern[(a2 - R16)*132 + b2] = e2;
            if (b2 >= R16 && b2 < R16 + 16) kern[(b2 - R16)*132 + a2] = e2;
        }
        if (tid < 16) kern[tid*132 + R16 + tid] = 1.0f;   // exp(0) diagonal
    }
    __syncthreads();

    //===== rowsum of kern strip ===============================================
    float* rsp    = &smem[OFF_MISC + 4];     // [8][16]
    float* rowsum = &smem[OFF_MISC + 132];   // [16]
    if (tid < 128) {
        const int row = tid & 15, ch = tid >> 4;
        float s = 0.f;
        #pragma unroll
        for (int e = 0; e < 16; ++e) s += kern[row*132 + ch*16 + e];
        rsp[ch*16 + row] = s;
    }
    __syncthreads();
    if (tid < 16) {
        float s = 0.f;
        #pragma unroll
        for (int ch = 0; ch < 8; ++ch) s += rsp[ch*16 + tid];
        rowsum[tid] = s;
    }
    __syncthreads();

    //===== A strip: A = kern + (invh/128)(kern@P - rowsum*P) ==================
    float* A = &smem[OFF_PJ];    // alias (Pj dead) [16][132]
    {
        const int r16 = tid >> 4, c8 = tid & 15;
        const float* krow = &kern[r16*132];
        float acc[8];
        #pragma unroll
        for (int e = 0; e < 8; ++e) acc[e] = 0.f;
        for (int m = 0; m < NP; ++m) {
            const float kf = krow[m];
            const float4 p0 = *(const float4*)&smem[OFF_PR + m*132 + 8*c8];
            const float4 p1 = *(const float4*)&smem[OFF_PR + m*132 + 8*c8 + 4];
            acc[0] = fmaf(kf, p0.x, acc[0]); acc[1] = fmaf(kf, p0.y, acc[1]);
            acc[2] = fmaf(kf, p0.z, acc[2]); acc[3] = fmaf(kf, p0.w, acc[3]);
            acc[4] = fmaf(kf, p1.x, acc[4]); acc[5] = fmaf(kf, p1.y, acc[5]);
            acc[6] = fmaf(kf, p1.z, acc[6]); acc[7] = fmaf(kf, p1.w, acc[7]);
        }
        const float sc = invh * (1.0f / 128.0f);
        const float rs = rowsum[r16];
        const int   ig = R16 + r16;
        float o[8];
        #pragma unroll
        for (int e = 0; e < 8; ++e)
            o[e] = krow[8*c8 + e] + sc * (acc[e] - rs * smem[OFF_PR + ig*132 + 8*c8 + e]);
        float4 o0 = {o[0], o[1], o[2], o[3]}, o1 = {o[4], o[5], o[6], o[7]};
        __syncthreads();            // everyone done reading Pj-alias? (Pj unused; guard A-write vs nothing stale)
        *(float4*)&A[r16*132 + 8*c8]     = o0;
        *(float4*)&A[r16*132 + 8*c8 + 4] = o1;
    }
    __syncthreads();

    //===== out tile = A_strip @ grad  (16 rows x 128 cols per block) ==========
    {
        const int CG  = (b & 15) * 128;
        const int r16 = tid >> 4, c16 = tid & 15;
        const float* Ar = &A[r16*132];
        float acc[8];
        #pragma unroll
        for (int e = 0; e < 8; ++e) acc[e] = 0.f;
        for (int m = 0; m < NP; ++m) {
            const float av = Ar[m];
            const float4 g0 = *(const float4*)&grad[m*DIM + CG + 8*c16];
            const float4 g1 = *(const float4*)&grad[m*DIM + CG + 8*c16 + 4];
            acc[0] = fmaf(av, g0.x, acc[0]); acc[1] = fmaf(av, g0.y, acc[1]);
            acc[2] = fmaf(av, g0.z, acc[2]); acc[3] = fmaf(av, g0.w, acc[3]);
            acc[4] = fmaf(av, g1.x, acc[4]); acc[5] = fmaf(av, g1.y, acc[5]);
            acc[6] = fmaf(av, g1.z, acc[6]); acc[7] = fmaf(av, g1.w, acc[7]);
        }
        const float4 o0 = {acc[0], acc[1], acc[2], acc[3]};
        const float4 o1 = {acc[4], acc[5], acc[6], acc[7]};
        float* op = out + (R16 + r16) * DIM + CG + 8*c16;
        *(float4*)op       = o0;
        *(float4*)(op + 4) = o1;
    }
}

// ---------------------------------------------------------------------------
extern "C" void kernel_launch(void* const* d_in, const int* in_sizes, int n_in,
                              void* d_out, int out_size, void* d_ws, size_t ws_size,
                              hipStream_t stream) {
    const float* var  = (const float*)d_in[0];
    const float* grad = (const float*)d_in[1];
    float* out = (float*)d_out;

    float*    Ppart = (float*)d_ws;                    // 8 * 16384 f32 = 512 KB
    unsigned* slots = (unsigned*)(Ppart + 8 * NP * NP); // 128 u32 (poisoned 0xAA)

    hipFuncSetAttribute((const void*)stein_fused,
                        hipFuncAttributeMaxDynamicSharedMemorySize,
                        LDS_FLOATS * 4);

    void* args[] = { (void*)&var, (void*)&grad, (void*)&out,
                     (void*)&Ppart, (void*)&slots };
    hipLaunchCooperativeKernel((const void*)stein_fused, dim3(NBLK), dim3(NTHR),
                               args, LDS_FLOATS * 4, stream);
}

// Round 5
// 137.083 us; speedup vs baseline: 1.2481x; 1.2481x over previous
//
#include <hip/hip_runtime.h>
#include <math.h>

#define NP   128
#define DIM  2048
#define NTHR 256

// ============================ K1: P partials ================================
// 16 output tiles (32x32) x 8 K-chunks = 128 blocks. Plain stores to Ppart.
__global__ __launch_bounds__(NTHR) void k_pmat(const float* __restrict__ var,
                                               const float* __restrict__ grad,
                                               float* __restrict__ Ppart) {
    __shared__ float At[64 * 36];   // [k][row] k-major var rows
    __shared__ float Bt[64 * 36];
    const int tid = threadIdx.x;
    const int b   = blockIdx.x;
    const int t   = b & 15;
    const int ck  = b >> 4;
    const int i0  = (t >> 2) * 32;
    const int j0  = (t & 3) * 32;
    const int tx  = tid & 15, ty = tid >> 4;
    const int lrow = 2 * ty + (tx >> 3);   // 0..31
    const int lcol = 4 * (tx & 7);         // 0,4,..,28
    float4 acc = {0.f, 0.f, 0.f, 0.f};
    for (int s = 0; s < 4; ++s) {
        const int kb = ck * 256 + s * 64;
        __syncthreads();
        #pragma unroll
        for (int p = 0; p < 2; ++p) {
            const int f  = tid + p * 256;
            const int r  = f >> 4;
            const int kq = (f & 15) * 4;
            const float4 a4 = *(const float4*)(var  + (i0 + r) * DIM + kb + kq);
            const float4 g4 = *(const float4*)(grad + (j0 + r) * DIM + kb + kq);
            At[(kq+0)*36 + r] = a4.x; At[(kq+1)*36 + r] = a4.y;
            At[(kq+2)*36 + r] = a4.z; At[(kq+3)*36 + r] = a4.w;
            Bt[(kq+0)*36 + r] = g4.x; Bt[(kq+1)*36 + r] = g4.y;
            Bt[(kq+2)*36 + r] = g4.z; Bt[(kq+3)*36 + r] = g4.w;
        }
        __syncthreads();
        #pragma unroll 8
        for (int k = 0; k < 64; ++k) {
            const float  a  = At[k*36 + lrow];
            const float4 b4 = *(const float4*)&Bt[k*36 + lcol];
            acc.x = fmaf(a, b4.x, acc.x);
            acc.y = fmaf(a, b4.y, acc.y);
            acc.z = fmaf(a, b4.z, acc.z);
            acc.w = fmaf(a, b4.w, acc.w);
        }
    }
    *(float4*)(Ppart + ck * (NP*NP) + (i0 + lrow) * NP + j0 + lcol) = acc;
}

// ============================ K2: everything else ===========================
// Dynamic LDS layout (float offsets). 145,920 B (<160 KiB/CU, 1 blk/CU).
#define OFF_PJ   0          // Pj[j][i]  128x132  (column-major P; Gram reads)
#define OFF_PR   16896      // Pr[i][j]  128x132  (row-major P; A-phase reads)
#define OFF_KERN 33792      // kern[16][132]
#define OFF_D    35904      // D[128]  (|P_i|^2)
#define OFF_BINS 36032      // bins[256] (uint)
#define OFF_MISC 36288      // [0]=sel [1]=want | +4: rs_part[8][16] | +132: rowsum[16]
#define LDS_FLOATS 36480

extern __shared__ float smem[];

__device__ inline void diag_decode(int q, int& a, int& b) {
    // q in [0,448): strict-upper pair within an 8-aligned diagonal tile
    const int T = q / 28;
    int u = q - 28 * T, r = 0;
    while (u >= 7 - r) { u -= 7 - r; ++r; }
    a = 8 * T + r;
    b = 8 * T + r + 1 + u;
}

__global__ __launch_bounds__(NTHR, 1) void k_rest(const float* __restrict__ grad,
                                                  const float* __restrict__ Ppart,
                                                  float* __restrict__ out) {
    const int tid = threadIdx.x;
    const int b   = blockIdx.x;

    //===== Assembly: P = sum of 8 partials -> LDS in both layouts =============
    {
        const int i  = tid >> 1;
        const int jh = (tid & 1) * 64;
        float4 s[16];
        #pragma unroll
        for (int q = 0; q < 16; ++q) s[q] = {0.f, 0.f, 0.f, 0.f};
        for (int c = 0; c < 8; ++c) {
            const float* src = Ppart + c * (NP*NP) + i * NP + jh;
            #pragma unroll
            for (int q = 0; q < 16; ++q) {
                const float4 v = *(const float4*)(src + 4*q);
                s[q].x += v.x; s[q].y += v.y; s[q].z += v.z; s[q].w += v.w;
            }
        }
        #pragma unroll
        for (int q = 0; q < 16; ++q) {
            *(float4*)&smem[OFF_PR + i*132 + jh + 4*q] = s[q];
            const int j = jh + 4*q;
            smem[OFF_PJ + (j+0)*132 + i] = s[q].x;
            smem[OFF_PJ + (j+1)*132 + i] = s[q].y;
            smem[OFF_PJ + (j+2)*132 + i] = s[q].z;
            smem[OFF_PJ + (j+3)*132 + i] = s[q].w;
        }
    }
    __syncthreads();

    //===== Diag-tile pairs (448 same-8-group dots) + row norms D ==============
    float dv1 = 0.f, dv2 = 0.f, dnorm = 0.f;
    int a1, b1, a2 = 0, b2 = 0;
    const bool has2 = (tid < 192);
    diag_decode(tid, a1, b1);
    if (has2) diag_decode(256 + tid, a2, b2);
    const bool hasNorm = (tid < NP);
    for (int j = 0; j < NP; ++j) {
        const float* pj = &smem[OFF_PJ + j*132];
        dv1 = fmaf(pj[a1], pj[b1], dv1);
        dv2 = fmaf(pj[a2], pj[b2], dv2);
        if (hasNorm) dnorm = fmaf(pj[tid], pj[tid], dnorm);
    }
    if (hasNorm) smem[OFF_D + tid] = dnorm;

    //===== Strict-upper Gram: 120 tiles (8x8), 2 threads/tile (k-halves) ======
    float gacc[64];
    #pragma unroll
    for (int u = 0; u < 64; ++u) gacc[u] = 0.f;
    int sty = 0, stx = 1;
    const int shalf = tid & 1;
    if (tid < 240) {
        const int sq = tid >> 1;
        int y = 0, base = 0;
        while (base + (15 - y) <= sq) { base += 15 - y; ++y; }
        sty = y; stx = y + 1 + (sq - base);
        const int j0s = shalf * 64;
        for (int j = j0s; j < j0s + 64; ++j) {
            const float* pj = &smem[OFF_PJ + j*132];
            float av[8], bv[8];
            { const float4 q0 = *(const float4*)&pj[8*sty];
              const float4 q1 = *(const float4*)&pj[8*sty + 4];
              av[0]=q0.x; av[1]=q0.y; av[2]=q0.z; av[3]=q0.w;
              av[4]=q1.x; av[5]=q1.y; av[6]=q1.z; av[7]=q1.w; }
            { const float4 q0 = *(const float4*)&pj[8*stx];
              const float4 q1 = *(const float4*)&pj[8*stx + 4];
              bv[0]=q0.x; bv[1]=q0.y; bv[2]=q0.z; bv[3]=q0.w;
              bv[4]=q1.x; bv[5]=q1.y; bv[6]=q1.z; bv[7]=q1.w; }
            #pragma unroll
            for (int r = 0; r < 8; ++r)
                #pragma unroll
                for (int c = 0; c < 8; ++c)
                    gacc[r*8+c] = fmaf(av[r], bv[c], gacc[r*8+c]);
        }
    }
    // combine k-halves (pair = adjacent lanes)
    #pragma unroll
    for (int u = 0; u < 64; ++u)
        gacc[u] += __shfl_xor(gacc[u], 1);

    __syncthreads();   // D visible

    //===== Convert Gram -> dMsd values (in registers) =========================
    if (tid < 240) {
        float Da[8], Db[8];
        #pragma unroll
        for (int e = 0; e < 8; ++e) {
            Da[e] = smem[OFF_D + 8*sty + e];
            Db[e] = smem[OFF_D + 8*stx + e];
        }
        #pragma unroll
        for (int u = 0; u < 64; ++u)
            gacc[u] = (Da[u>>3] + Db[u&7] - 2.0f*gacc[u]) * (1.0f/128.0f);
    }
    dv1 = (smem[OFF_D + a1] + smem[OFF_D + b1] - 2.0f*dv1) * (1.0f/128.0f);
    if (has2)
        dv2 = (smem[OFF_D + a2] + smem[OFF_D + b2] - 2.0f*dv2) * (1.0f/128.0f);

    //===== Exact median: 4-pass weighted radix-select (rank 8192) =============
    // weights: each strict-upper value x2, plus 128 virtual zeros (true diag).
    unsigned* bins = (unsigned*)&smem[OFF_BINS];
    unsigned* sel  = (unsigned*)&smem[OFF_MISC];
    unsigned prefix = 0, want = 8192;
    for (int pass = 0; pass < 4; ++pass) {
        const int sh = 24 - 8*pass;
        bins[tid] = 0u;
        __syncthreads();
        if (tid < 240 && shalf == 0) {
            #pragma unroll
            for (int u = 0; u < 64; ++u) {
                const unsigned v = __float_as_uint(gacc[u]);
                if (pass == 0 || (v >> (sh + 8)) == prefix)
                    atomicAdd(&bins[(v >> sh) & 255u], 2u);
            }
        }
        { const unsigned v = __float_as_uint(dv1);
          if (pass == 0 || (v >> (sh + 8)) == prefix)
              atomicAdd(&bins[(v >> sh) & 255u], 2u); }
        if (has2) {
            const unsigned v = __float_as_uint(dv2);
            if (pass == 0 || (v >> (sh + 8)) == prefix)
                atomicAdd(&bins[(v >> sh) & 255u], 2u);
        }
        if (tid == 0 && prefix == 0) atomicAdd(&bins[0], 128u);  // true-diag zeros
        __syncthreads();
        if (tid < 64) {
            unsigned c0 = bins[4*tid], c1 = bins[4*tid+1], c2 = bins[4*tid+2], c3 = bins[4*tid+3];
            const unsigned tot = c0 + c1 + c2 + c3;
            unsigned incl = tot;
            #pragma unroll
            for (int o = 1; o < 64; o <<= 1) {
                const unsigned n = __shfl_up(incl, o);
                if (tid >= o) incl += n;
            }
            unsigned cum = incl - tot;
            unsigned cc[4] = {c0, c1, c2, c3};
            #pragma unroll
            for (int e = 0; e < 4; ++e) {
                if (cum <= want && want < cum + cc[e]) {
                    sel[0] = (unsigned)(4*tid + e);
                    sel[1] = want - cum;
                }
                cum += cc[e];
            }
        }
        __syncthreads();
        prefix = (prefix << 8) | sel[0];
        want = sel[1];
        __syncthreads();
    }
    const float med   = __uint_as_float(prefix);
    const float h     = med * med * (1.0f / 4.852030263919617f);  // /ln(128)
    const float inv2h = 0.5f / h;
    const float invh  = 1.0f / h;

    //===== kern strip (rows R16..R16+15) for this block's out tile ============
    const int rg  = b >> 4;          // 0..7 row-group
    const int R16 = rg * 16;
    float* kern = &smem[OFF_KERN];   // [16][132]
    {
        const int tp0 = 2*rg, tp1 = 2*rg + 1;
        if (tid < 240 && shalf == 0) {
            const bool rmatch = (sty == tp0) | (sty == tp1);
            const bool cmatch = (stx == tp0) | (stx == tp1);
            if (rmatch | cmatch) {
                #pragma unroll
                for (int u = 0; u < 64; ++u) {
                    const float e = __expf(-gacc[u] * inv2h);
                    const int aa = 8*sty + (u >> 3), bb = 8*stx + (u & 7);
                    if (rmatch) kern[(aa - R16)*132 + bb] = e;
                    if (cmatch) kern[(bb - R16)*132 + aa] = e;
                }
            }
        }
        { const float e1 = __expf(-dv1 * inv2h);
          if (a1 >= R16 && a1 < R16 + 16) kern[(a1 - R16)*132 + b1] = e1;
          if (b1 >= R16 && b1 < R16 + 16) kern[(b1 - R16)*132 + a1] = e1; }
        if (has2) {
            const float e2 = __expf(-dv2 * inv2h);
            if (a2 >= R16 && a2 < R16 + 16) kern[(a2 - R16)*132 + b2] = e2;
            if (b2 >= R16 && b2 < R16 + 16) kern[(b2 - R16)*132 + a2] = e2;
        }
        if (tid < 16) kern[tid*132 + R16 + tid] = 1.0f;   // exp(0) diagonal
    }
    __syncthreads();

    //===== rowsum of kern strip ===============================================
    float* rsp    = &smem[OFF_MISC + 4];     // [8][16]
    float* rowsum = &smem[OFF_MISC + 132];   // [16]
    if (tid < 128) {
        const int row = tid & 15, ch = tid >> 4;
        float s = 0.f;
        #pragma unroll
        for (int e = 0; e < 16; ++e) s += kern[row*132 + ch*16 + e];
        rsp[ch*16 + row] = s;
    }
    __syncthreads();
    if (tid < 16) {
        float s = 0.f;
        #pragma unroll
        for (int ch = 0; ch < 8; ++ch) s += rsp[ch*16 + tid];
        rowsum[tid] = s;
    }
    __syncthreads();

    //===== A strip: A = kern + (invh/128)(kern@P - rowsum*P) ==================
    float* A = &smem[OFF_PJ];    // alias (Pj dead) [16][132]
    {
        const int r16 = tid >> 4, c8 = tid & 15;
        const float* krow = &kern[r16*132];
        float acc[8];
        #pragma unroll
        for (int e = 0; e < 8; ++e) acc[e] = 0.f;
        for (int m = 0; m < NP; ++m) {
            const float kf = krow[m];
            const float4 p0 = *(const float4*)&smem[OFF_PR + m*132 + 8*c8];
            const float4 p1 = *(const float4*)&smem[OFF_PR + m*132 + 8*c8 + 4];
            acc[0] = fmaf(kf, p0.x, acc[0]); acc[1] = fmaf(kf, p0.y, acc[1]);
            acc[2] = fmaf(kf, p0.z, acc[2]); acc[3] = fmaf(kf, p0.w, acc[3]);
            acc[4] = fmaf(kf, p1.x, acc[4]); acc[5] = fmaf(kf, p1.y, acc[5]);
            acc[6] = fmaf(kf, p1.z, acc[6]); acc[7] = fmaf(kf, p1.w, acc[7]);
        }
        const float sc = invh * (1.0f / 128.0f);
        const float rs = rowsum[r16];
        const int   ig = R16 + r16;
        float o[8];
        #pragma unroll
        for (int e = 0; e < 8; ++e)
            o[e] = krow[8*c8 + e] + sc * (acc[e] - rs * smem[OFF_PR + ig*132 + 8*c8 + e]);
        float4 o0 = {o[0], o[1], o[2], o[3]}, o1 = {o[4], o[5], o[6], o[7]};
        __syncthreads();
        *(float4*)&A[r16*132 + 8*c8]     = o0;
        *(float4*)&A[r16*132 + 8*c8 + 4] = o1;
    }
    __syncthreads();

    //===== out tile = A_strip @ grad  (16 rows x 128 cols per block) ==========
    {
        const int CG  = (b & 15) * 128;
        const int r16 = tid >> 4, c16 = tid & 15;
        const float* Ar = &A[r16*132];
        float acc[8];
        #pragma unroll
        for (int e = 0; e < 8; ++e) acc[e] = 0.f;
        for (int m = 0; m < NP; ++m) {
            const float av = Ar[m];
            const float4 g0 = *(const float4*)&grad[m*DIM + CG + 8*c16];
            const float4 g1 = *(const float4*)&grad[m*DIM + CG + 8*c16 + 4];
            acc[0] = fmaf(av, g0.x, acc[0]); acc[1] = fmaf(av, g0.y, acc[1]);
            acc[2] = fmaf(av, g0.z, acc[2]); acc[3] = fmaf(av, g0.w, acc[3]);
            acc[4] = fmaf(av, g1.x, acc[4]); acc[5] = fmaf(av, g1.y, acc[5]);
            acc[6] = fmaf(av, g1.z, acc[6]); acc[7] = fmaf(av, g1.w, acc[7]);
        }
        const float4 o0 = {acc[0], acc[1], acc[2], acc[3]};
        const float4 o1 = {acc[4], acc[5], acc[6], acc[7]};
        float* op = out + (R16 + r16) * DIM + CG + 8*c16;
        *(float4*)op       = o0;
        *(float4*)(op + 4) = o1;
    }
}

// ---------------------------------------------------------------------------
extern "C" void kernel_launch(void* const* d_in, const int* in_sizes, int n_in,
                              void* d_out, int out_size, void* d_ws, size_t ws_size,
                              hipStream_t stream) {
    const float* var  = (const float*)d_in[0];
    const float* grad = (const float*)d_in[1];
    float* out = (float*)d_out;

    float* Ppart = (float*)d_ws;     // 8 * 16384 f32 = 512 KB

    hipFuncSetAttribute((const void*)k_rest,
                        hipFuncAttributeMaxDynamicSharedMemorySize,
                        LDS_FLOATS * 4);

    k_pmat<<<dim3(128), dim3(NTHR), 0,              stream>>>(var, grad, Ppart);
    k_rest<<<dim3(128), dim3(NTHR), LDS_FLOATS * 4, stream>>>(grad, Ppart, out);
}

// Round 7
// 129.827 us; speedup vs baseline: 1.3179x; 1.0559x over previous
//
#include <hip/hip_runtime.h>
#include <math.h>

#define NP   128
#define DIM  2048
#define NTHR 256

// ============================ K1: P partials ================================
// 16 output tiles (32x32) x 8 K-chunks = 128 blocks. Plain stores to Ppart.
__global__ __launch_bounds__(NTHR) void k_pmat(const float* __restrict__ var,
                                               const float* __restrict__ grad,
                                               float* __restrict__ Ppart) {
    __shared__ float At[64 * 36];   // [k][row] k-major var rows
    __shared__ float Bt[64 * 36];
    const int tid = threadIdx.x;
    const int b   = blockIdx.x;
    const int t   = b & 15;
    const int ck  = b >> 4;
    const int i0  = (t >> 2) * 32;
    const int j0  = (t & 3) * 32;
    const int tx  = tid & 15, ty = tid >> 4;
    const int lrow = 2 * ty + (tx >> 3);   // 0..31
    const int lcol = 4 * (tx & 7);         // 0,4,..,28
    float4 acc = {0.f, 0.f, 0.f, 0.f};
    for (int s = 0; s < 4; ++s) {
        const int kb = ck * 256 + s * 64;
        __syncthreads();
        #pragma unroll
        for (int p = 0; p < 2; ++p) {
            const int f  = tid + p * 256;
            const int r  = f >> 4;
            const int kq = (f & 15) * 4;
            const float4 a4 = *(const float4*)(var  + (i0 + r) * DIM + kb + kq);
            const float4 g4 = *(const float4*)(grad + (j0 + r) * DIM + kb + kq);
            At[(kq+0)*36 + r] = a4.x; At[(kq+1)*36 + r] = a4.y;
            At[(kq+2)*36 + r] = a4.z; At[(kq+3)*36 + r] = a4.w;
            Bt[(kq+0)*36 + r] = g4.x; Bt[(kq+1)*36 + r] = g4.y;
            Bt[(kq+2)*36 + r] = g4.z; Bt[(kq+3)*36 + r] = g4.w;
        }
        __syncthreads();
        #pragma unroll 8
        for (int k = 0; k < 64; ++k) {
            const float  a  = At[k*36 + lrow];
            const float4 b4 = *(const float4*)&Bt[k*36 + lcol];
            acc.x = fmaf(a, b4.x, acc.x);
            acc.y = fmaf(a, b4.y, acc.y);
            acc.z = fmaf(a, b4.z, acc.z);
            acc.w = fmaf(a, b4.w, acc.w);
        }
    }
    *(float4*)(Ppart + ck * (NP*NP) + (i0 + lrow) * NP + j0 + lcol) = acc;
}

// ============================ K2: P + dMsd ==================================
// 16 blocks. Each assembles full P in LDS, computes D = |P_i|^2, then its
// 8-row strip of dMsd[i][j] = (D[i] + D[j] - 2 P_i.P_j)/128. Block b also
// writes P rows 8b..8b+8 to global.
extern __shared__ float k2smem[];   // Pr[128][132] + Dsh[128] = 68,096 B

__global__ __launch_bounds__(NTHR) void k_dmsd(const float* __restrict__ Ppart,
                                               float* __restrict__ P,
                                               float* __restrict__ dMsd) {
    float* Pr  = k2smem;            // [128][132]
    float* Dsh = k2smem + NP * 132; // [128]
    const int tid = threadIdx.x;
    const int b   = blockIdx.x;

    // assemble: thread -> row i = tid>>1, half jh = (tid&1)*64 (16 float4)
    {
        const int i  = tid >> 1;
        const int jh = (tid & 1) * 64;
        float4 s[16];
        #pragma unroll
        for (int q = 0; q < 16; ++q) s[q] = {0.f, 0.f, 0.f, 0.f};
        for (int c = 0; c < 8; ++c) {
            const float* src = Ppart + c * (NP*NP) + i * NP + jh;
            #pragma unroll
            for (int q = 0; q < 16; ++q) {
                const float4 v = *(const float4*)(src + 4*q);
                s[q].x += v.x; s[q].y += v.y; s[q].z += v.z; s[q].w += v.w;
            }
        }
        #pragma unroll
        for (int q = 0; q < 16; ++q)
            *(float4*)&Pr[i*132 + jh + 4*q] = s[q];
    }
    __syncthreads();

    // write P strip rows 8b..8b+8 (1024 floats; 4 per thread)
    {
        const int f = tid * 4;
        const int r = f >> 7;        // 0..7
        const int c = f & 127;
        *(float4*)(P + (8*b + r) * NP + c) = *(const float4*)&Pr[(8*b + r)*132 + c];
    }

    // D = row norms
    if (tid < NP) {
        float acc = 0.f;
        #pragma unroll 8
        for (int k = 0; k < NP; k += 4) {
            const float4 p = *(const float4*)&Pr[tid*132 + k];
            acc = fmaf(p.x, p.x, acc);
            acc = fmaf(p.y, p.y, acc);
            acc = fmaf(p.z, p.z, acc);
            acc = fmaf(p.w, p.w, acc);
        }
        Dsh[tid] = acc;
    }
    __syncthreads();

    // strip Gram: rows r0..r0+3 (half = tid>>7), col x = tid&127
    const int x  = tid & 127;
    const int r0 = 8*b + (tid >> 7) * 4;
    float a0 = 0.f, a1 = 0.f, a2 = 0.f, a3 = 0.f;
    #pragma unroll 4
    for (int m = 0; m < NP; ++m) {
        const float pm = Pr[x*132 + m];
        a0 = fmaf(Pr[(r0+0)*132 + m], pm, a0);   // broadcast reads
        a1 = fmaf(Pr[(r0+1)*132 + m], pm, a1);
        a2 = fmaf(Pr[(r0+2)*132 + m], pm, a2);
        a3 = fmaf(Pr[(r0+3)*132 + m], pm, a3);
    }
    const float Dx = Dsh[x];
    dMsd[(r0+0)*NP + x] = (Dsh[r0+0] + Dx - 2.f*a0) * (1.f/128.f);
    dMsd[(r0+1)*NP + x] = (Dsh[r0+1] + Dx - 2.f*a1) * (1.f/128.f);
    dMsd[(r0+2)*NP + x] = (Dsh[r0+2] + Dx - 2.f*a2) * (1.f/128.f);
    dMsd[(r0+3)*NP + x] = (Dsh[r0+3] + Dx - 2.f*a3) * (1.f/128.f);
}

// ============================ K3: median + A + out ==========================
// 256 blocks: rg = b>>4 (8-row strip), cg = b&15 (128-col group).
// Each block: register-resident exact median (rank 8192), kern strip,
// A = kern + (1/(128h))(kern@P - rowsum*P), out = A @ grad.
__global__ __launch_bounds__(NTHR) void k_out(const float* __restrict__ P,
                                              const float* __restrict__ dMsd,
                                              const float* __restrict__ grad,
                                              float* __restrict__ out) {
    __shared__ float    kern[8 * 132];
    __shared__ float    Ash[8 * 132];
    __shared__ unsigned uparts[2][4];
    __shared__ float    rsp[4][4];      // [wave][q] partial rowsums

    const int tid  = threadIdx.x;
    const int b    = blockIdx.x;
    const int R8   = (b >> 4) * 8;
    const int CG   = (b & 15) * 128;
    const int j    = tid & 127;
    const int half = tid >> 7;          // 0/1
    const int rb   = half * 4;
    const int wid  = tid >> 6;

    //----- load all dMsd into registers (clamp >=0 so uint order == float order)
    unsigned v[64];
    #pragma unroll
    for (int u = 0; u < 64; ++u)
        v[u] = __float_as_uint(fmaxf(dMsd[u * 256 + tid], 0.f));

    //----- exact median, rank 8192 (0-indexed; nearest of 0.5*16383) ----------
    unsigned lo = 0u;
    for (int bit = 30; bit >= 0; --bit) {
        const unsigned mid = lo | (1u << bit);
        unsigned cnt = 0;
        #pragma unroll
        for (int u = 0; u < 64; ++u) cnt += (v[u] < mid) ? 1u : 0u;
        #pragma unroll
        for (int o = 32; o > 0; o >>= 1) cnt += __shfl_down(cnt, o);
        if ((tid & 63) == 0) uparts[bit & 1][wid] = cnt;
        __syncthreads();
        const unsigned total = uparts[bit & 1][0] + uparts[bit & 1][1]
                             + uparts[bit & 1][2] + uparts[bit & 1][3];
        if (total <= 8192u) lo = mid;   // same on every thread
    }
    const float med   = __uint_as_float(lo);
    const float h     = med * med * (1.0f / 4.852030263919617f);   // /ln(128)
    const float inv2h = 0.5f / h;
    const float invh  = 1.0f / h;

    //----- kern strip rows R8+rb..+3, col j ----------------------------------
    float kv[4];
    #pragma unroll
    for (int q = 0; q < 4; ++q) {
        kv[q] = __expf(-dMsd[(R8 + rb + q) * NP + j] * inv2h);
        kern[(rb + q) * 132 + j] = kv[q];
    }
    // per-wave rowsum partials (each wave spans 64 consecutive j of one half)
    #pragma unroll
    for (int q = 0; q < 4; ++q) {
        float t = kv[q];
        #pragma unroll
        for (int o = 32; o > 0; o >>= 1) t += __shfl_down(t, o);
        if ((tid & 63) == 0) rsp[wid][q] = t;
    }
    __syncthreads();
    float rsum[4];
    #pragma unroll
    for (int q = 0; q < 4; ++q)
        rsum[q] = rsp[2 * half][q] + rsp[2 * half + 1][q];

    //----- A strip: A = kern + (invh/128)(kern@P - rowsum*P) ------------------
    {
        float acc[4] = {0.f, 0.f, 0.f, 0.f};
        #pragma unroll 4
        for (int m = 0; m < NP; ++m) {
            const float pc = P[m * NP + j];          // coalesced, L2-hot
            acc[0] = fmaf(kern[(rb+0)*132 + m], pc, acc[0]);  // LDS broadcast
            acc[1] = fmaf(kern[(rb+1)*132 + m], pc, acc[1]);
            acc[2] = fmaf(kern[(rb+2)*132 + m], pc, acc[2]);
            acc[3] = fmaf(kern[(rb+3)*132 + m], pc, acc[3]);
        }
        const float sc = invh * (1.0f / 128.0f);
        #pragma unroll
        for (int q = 0; q < 4; ++q) {
            const float Pi = P[(R8 + rb + q) * NP + j];
            Ash[(rb + q) * 132 + j] = kv[q] + sc * (acc[q] - rsum[q] * Pi);
        }
    }
    __syncthreads();

    //----- out tile: rows R8+rb..+3, col CG+j --------------------------------
    {
        float acc[4] = {0.f, 0.f, 0.f, 0.f};
        #pragma unroll 4
        for (int m = 0; m < NP; ++m) {
            const float g = grad[m * DIM + CG + j];  // coalesced, L2/L3-hot
            acc[0] = fmaf(Ash[(rb+0)*132 + m], g, acc[0]);    // LDS broadcast
            acc[1] = fmaf(Ash[(rb+1)*132 + m], g, acc[1]);
            acc[2] = fmaf(Ash[(rb+2)*132 + m], g, acc[2]);
            acc[3] = fmaf(Ash[(rb+3)*132 + m], g, acc[3]);
        }
        #pragma unroll
        for (int q = 0; q < 4; ++q)
            out[(R8 + rb + q) * DIM + CG + j] = acc[q];
    }
}

// ---------------------------------------------------------------------------
extern "C" void kernel_launch(void* const* d_in, const int* in_sizes, int n_in,
                              void* d_out, int out_size, void* d_ws, size_t ws_size,
                              hipStream_t stream) {
    const float* var  = (const float*)d_in[0];
    const float* grad = (const float*)d_in[1];
    float* out = (float*)d_out;

    float* Ppart = (float*)d_ws;            // 8 * 16384 f32 = 512 KB
    float* P     = Ppart + 8 * NP * NP;     // 16384 f32
    float* dMsd  = P + NP * NP;             // 16384 f32

    const int k2_lds = (NP * 132 + NP) * 4; // 68,096 B
    hipFuncSetAttribute((const void*)k_dmsd,
                        hipFuncAttributeMaxDynamicSharedMemorySize, k2_lds);

    k_pmat<<<dim3(128), dim3(NTHR), 0,      stream>>>(var, grad, Ppart);
    k_dmsd<<<dim3(16),  dim3(NTHR), k2_lds, stream>>>(Ppart, P, dMsd);
    k_out <<<dim3(256), dim3(NTHR), 0,      stream>>>(P, dMsd, grad, out);
}

// Round 8
// 126.756 us; speedup vs baseline: 1.3498x; 1.0242x over previous
//
#include <hip/hip_runtime.h>
#include <math.h>

#define NP   128
#define DIM  2048
#define NTHR 256

// ============================ K1: P partials ================================
// 16 output tiles (32x32) x 8 K-chunks = 128 blocks. Plain stores to Ppart.
__global__ __launch_bounds__(NTHR) void k_pmat(const float* __restrict__ var,
                                               const float* __restrict__ grad,
                                               float* __restrict__ Ppart) {
    __shared__ float At[64 * 36];   // [k][row] k-major var rows
    __shared__ float Bt[64 * 36];
    const int tid = threadIdx.x;
    const int b   = blockIdx.x;
    const int t   = b & 15;
    const int ck  = b >> 4;
    const int i0  = (t >> 2) * 32;
    const int j0  = (t & 3) * 32;
    const int tx  = tid & 15, ty = tid >> 4;
    const int lrow = 2 * ty + (tx >> 3);   // 0..31
    const int lcol = 4 * (tx & 7);         // 0,4,..,28
    float4 acc = {0.f, 0.f, 0.f, 0.f};
    for (int s = 0; s < 4; ++s) {
        const int kb = ck * 256 + s * 64;
        __syncthreads();
        #pragma unroll
        for (int p = 0; p < 2; ++p) {
            const int f  = tid + p * 256;
            const int r  = f >> 4;
            const int kq = (f & 15) * 4;
            const float4 a4 = *(const float4*)(var  + (i0 + r) * DIM + kb + kq);
            const float4 g4 = *(const float4*)(grad + (j0 + r) * DIM + kb + kq);
            At[(kq+0)*36 + r] = a4.x; At[(kq+1)*36 + r] = a4.y;
            At[(kq+2)*36 + r] = a4.z; At[(kq+3)*36 + r] = a4.w;
            Bt[(kq+0)*36 + r] = g4.x; Bt[(kq+1)*36 + r] = g4.y;
            Bt[(kq+2)*36 + r] = g4.z; Bt[(kq+3)*36 + r] = g4.w;
        }
        __syncthreads();
        #pragma unroll 8
        for (int k = 0; k < 64; ++k) {
            const float  a  = At[k*36 + lrow];
            const float4 b4 = *(const float4*)&Bt[k*36 + lcol];
            acc.x = fmaf(a, b4.x, acc.x);
            acc.y = fmaf(a, b4.y, acc.y);
            acc.z = fmaf(a, b4.z, acc.z);
            acc.w = fmaf(a, b4.w, acc.w);
        }
    }
    *(float4*)(Ppart + ck * (NP*NP) + (i0 + lrow) * NP + j0 + lcol) = acc;
}

// ============================ K2: P + dMsd ==================================
// 16 blocks. Each assembles full P in LDS, computes D = |P_i|^2, then its
// 8-row strip of dMsd[i][j] = (D[i] + D[j] - 2 P_i.P_j)/128. Block b also
// writes P rows 8b..8b+8 to global.
extern __shared__ float k2smem[];   // Pr[128][132] + Dsh[128] = 68,096 B

__global__ __launch_bounds__(NTHR) void k_dmsd(const float* __restrict__ Ppart,
                                               float* __restrict__ P,
                                               float* __restrict__ dMsd) {
    float* Pr  = k2smem;            // [128][132]
    float* Dsh = k2smem + NP * 132; // [128]
    const int tid = threadIdx.x;
    const int b   = blockIdx.x;

    // assemble: thread -> row i = tid>>1, half jh = (tid&1)*64 (16 float4)
    {
        const int i  = tid >> 1;
        const int jh = (tid & 1) * 64;
        float4 s[16];
        #pragma unroll
        for (int q = 0; q < 16; ++q) s[q] = {0.f, 0.f, 0.f, 0.f};
        for (int c = 0; c < 8; ++c) {
            const float* src = Ppart + c * (NP*NP) + i * NP + jh;
            #pragma unroll
            for (int q = 0; q < 16; ++q) {
                const float4 v = *(const float4*)(src + 4*q);
                s[q].x += v.x; s[q].y += v.y; s[q].z += v.z; s[q].w += v.w;
            }
        }
        #pragma unroll
        for (int q = 0; q < 16; ++q)
            *(float4*)&Pr[i*132 + jh + 4*q] = s[q];
    }
    __syncthreads();

    // write P strip rows 8b..8b+8 (1024 floats; 4 per thread)
    {
        const int f = tid * 4;
        const int r = f >> 7;        // 0..7
        const int c = f & 127;
        *(float4*)(P + (8*b + r) * NP + c) = *(const float4*)&Pr[(8*b + r)*132 + c];
    }

    // D = row norms
    if (tid < NP) {
        float acc = 0.f;
        #pragma unroll 8
        for (int k = 0; k < NP; k += 4) {
            const float4 p = *(const float4*)&Pr[tid*132 + k];
            acc = fmaf(p.x, p.x, acc);
            acc = fmaf(p.y, p.y, acc);
            acc = fmaf(p.z, p.z, acc);
            acc = fmaf(p.w, p.w, acc);
        }
        Dsh[tid] = acc;
    }
    __syncthreads();

    // strip Gram: rows r0..r0+3 (half = tid>>7), col x = tid&127
    const int x  = tid & 127;
    const int r0 = 8*b + (tid >> 7) * 4;
    float a0 = 0.f, a1 = 0.f, a2 = 0.f, a3 = 0.f;
    #pragma unroll 4
    for (int m = 0; m < NP; ++m) {
        const float pm = Pr[x*132 + m];
        a0 = fmaf(Pr[(r0+0)*132 + m], pm, a0);   // broadcast reads
        a1 = fmaf(Pr[(r0+1)*132 + m], pm, a1);
        a2 = fmaf(Pr[(r0+2)*132 + m], pm, a2);
        a3 = fmaf(Pr[(r0+3)*132 + m], pm, a3);
    }
    const float Dx = Dsh[x];
    dMsd[(r0+0)*NP + x] = (Dsh[r0+0] + Dx - 2.f*a0) * (1.f/128.f);
    dMsd[(r0+1)*NP + x] = (Dsh[r0+1] + Dx - 2.f*a1) * (1.f/128.f);
    dMsd[(r0+2)*NP + x] = (Dsh[r0+2] + Dx - 2.f*a2) * (1.f/128.f);
    dMsd[(r0+3)*NP + x] = (Dsh[r0+3] + Dx - 2.f*a3) * (1.f/128.f);
}

// ============================ K3: median + A + out ==========================
// 256 blocks x 1024 threads: rg = b>>4 (8-row strip), cg = b&15 (128 cols).
// Median: v[16]/thread IN REGISTERS (round-7's v[64]@256thr spilled: VGPR=44),
// 2 bits/iter -> 16 iterations. Then 1 kern/A/out element per thread.
__global__ __launch_bounds__(1024) void k_out(const float* __restrict__ P,
                                              const float* __restrict__ dMsd,
                                              const float* __restrict__ grad,
                                              float* __restrict__ out) {
    __shared__ float    kern[8 * 132];
    __shared__ float    Ash[8 * 132];
    __shared__ unsigned cnt_lds[2][16][3];   // double-buffered per-wave counts
    __shared__ float    rsp[16];             // per-wave rowsum partials

    const int tid = threadIdx.x;             // 0..1023
    const int b   = blockIdx.x;
    const int R8  = (b >> 4) * 8;
    const int CG  = (b & 15) * 128;
    const int wid = tid >> 6;                // 0..15
    const int r   = tid >> 7;                // 0..7
    const int j   = tid & 127;

    //----- load 16 dMsd vals into registers (clamp >=0: uint order==float order)
    unsigned v[16];
    #pragma unroll
    for (int u = 0; u < 16; ++u)
        v[u] = __float_as_uint(fmaxf(dMsd[u * 1024 + tid], 0.f));

    //----- exact median, rank 8192, 2 bits per iteration ----------------------
    // invariant: count(v < lo) <= 8192; pick largest of {lo|01,lo|10,lo|11}<<sh
    unsigned lo = 0u;
    for (int it = 15; it >= 0; --it) {
        const int sh = 2 * it;
        const unsigned m0 = lo | (1u << sh);
        const unsigned m1 = lo | (2u << sh);
        const unsigned m2 = lo | (3u << sh);
        unsigned c0 = 0, c1 = 0, c2 = 0;
        #pragma unroll
        for (int u = 0; u < 16; ++u) {
            c0 += (v[u] < m0) ? 1u : 0u;
            c1 += (v[u] < m1) ? 1u : 0u;
            c2 += (v[u] < m2) ? 1u : 0u;
        }
        #pragma unroll
        for (int o = 32; o > 0; o >>= 1) {   // 3 chains interleaved
            c0 += __shfl_down(c0, o);
            c1 += __shfl_down(c1, o);
            c2 += __shfl_down(c2, o);
        }
        if ((tid & 63) == 0) {
            cnt_lds[it & 1][wid][0] = c0;
            cnt_lds[it & 1][wid][1] = c1;
            cnt_lds[it & 1][wid][2] = c2;
        }
        __syncthreads();
        unsigned t0 = 0, t1 = 0, t2 = 0;
        #pragma unroll
        for (int w = 0; w < 16; ++w) {
            t0 += cnt_lds[it & 1][w][0];
            t1 += cnt_lds[it & 1][w][1];
            t2 += cnt_lds[it & 1][w][2];
        }
        if      (t2 <= 8192u) lo = m2;
        else if (t1 <= 8192u) lo = m1;
        else if (t0 <= 8192u) lo = m0;
    }
    const float med   = __uint_as_float(lo);
    const float h     = med * med * (1.0f / 4.852030263919617f);   // /ln(128)
    const float inv2h = 0.5f / h;
    const float invh  = 1.0f / h;

    //----- kern strip: 1 element/thread (row R8+r, col j) ---------------------
    const float kv = __expf(-dMsd[(R8 + r) * NP + j] * inv2h);
    kern[r * 132 + j] = kv;
    {   // rowsum: row r spans waves 2r, 2r+1
        float t = kv;
        #pragma unroll
        for (int o = 32; o > 0; o >>= 1) t += __shfl_down(t, o);
        if ((tid & 63) == 0) rsp[wid] = t;
    }
    __syncthreads();
    const float rs = rsp[2 * r] + rsp[2 * r + 1];

    //----- A: A[r][j] = kv + (invh/128)*(sum_m kern[r][m] P[m][j] - rs*P[R8+r][j])
    {
        float acc = 0.f;
        #pragma unroll 8
        for (int m = 0; m < NP; ++m)
            acc = fmaf(kern[r * 132 + m], P[m * NP + j], acc);  // bcast x coalesced
        const float Pi = P[(R8 + r) * NP + j];
        Ash[r * 132 + j] = kv + invh * (1.0f / 128.0f) * (acc - rs * Pi);
    }
    __syncthreads();

    //----- out: out[R8+r][CG+j] = sum_m A[r][m] grad[m][CG+j] -----------------
    {
        float acc = 0.f;
        #pragma unroll 8
        for (int m = 0; m < NP; ++m)
            acc = fmaf(Ash[r * 132 + m], grad[m * DIM + CG + j], acc);
        out[(R8 + r) * DIM + CG + j] = acc;
    }
}

// ---------------------------------------------------------------------------
extern "C" void kernel_launch(void* const* d_in, const int* in_sizes, int n_in,
                              void* d_out, int out_size, void* d_ws, size_t ws_size,
                              hipStream_t stream) {
    const float* var  = (const float*)d_in[0];
    const float* grad = (const float*)d_in[1];
    float* out = (float*)d_out;

    float* Ppart = (float*)d_ws;            // 8 * 16384 f32 = 512 KB
    float* P     = Ppart + 8 * NP * NP;     // 16384 f32
    float* dMsd  = P + NP * NP;             // 16384 f32

    const int k2_lds = (NP * 132 + NP) * 4; // 68,096 B
    hipFuncSetAttribute((const void*)k_dmsd,
                        hipFuncAttributeMaxDynamicSharedMemorySize, k2_lds);

    k_pmat<<<dim3(128), dim3(NTHR),  0,      stream>>>(var, grad, Ppart);
    k_dmsd<<<dim3(16),  dim3(NTHR),  k2_lds, stream>>>(Ppart, P, dMsd);
    k_out <<<dim3(256), dim3(1024),  0,      stream>>>(P, dMsd, grad, out);
}